// Round 6
// baseline (271.285 us; speedup 1.0000x reference)
//
#include <hip/hip_runtime.h>
#include <hip/hip_bf16.h>
#include <hip/hip_cooperative_groups.h>

namespace cg = cooperative_groups;

// Shapes hardcoded: b=16, S=512, IN=256, OUT=128, NB=6, Lo=256, actual_seq_len=512
#define LN_EPS 1e-5f

typedef __attribute__((ext_vector_type(8))) short short8;   // 8 bf16 = 4 VGPR (MFMA A/B frag)
typedef __attribute__((ext_vector_type(4))) float floatx4;  // MFMA C/D frag

__device__ __forceinline__ float bf2f(unsigned int u16) {
    union { unsigned int i; float f; } v; v.i = (u16 & 0xffffu) << 16; return v.f;
}
__device__ __forceinline__ unsigned short f2bf(float f) {
    __hip_bfloat16 h = __float2bfloat16(f);
    union { __hip_bfloat16 h; unsigned short u; } v; v.h = h; return v.u;
}
__device__ __forceinline__ unsigned int pack2(float a, float b) {
    return (unsigned int)f2bf(a) | ((unsigned int)f2bf(b) << 16);
}
__device__ __forceinline__ short8 pack8(float4 a, float4 b) {
    union { short8 s; uint4 u; } v;
    v.u.x = pack2(a.x, a.y); v.u.y = pack2(a.z, a.w);
    v.u.z = pack2(b.x, b.y); v.u.w = pack2(b.z, b.w);
    return v.s;
}

union SMem {
    struct { float buf[32 * 258]; float red1[256]; float red2[256]; float mus[32]; float rsg[32]; } p1;
    unsigned short lcat[32 * 260];
    float red[4 * 32 * 64];
};

// Single cooperative kernel: 512 blocks x 256 threads, 2 grid syncs.
__global__ __launch_bounds__(256, 2) void fused_all(const float* __restrict__ x,
                                                    const float* __restrict__ M,
                                                    const float* __restrict__ resW,
                                                    const float* __restrict__ gamma,
                                                    const float* __restrict__ beta,
                                                    const float* __restrict__ P,
                                                    const float* __restrict__ periods,
                                                    const float* __restrict__ Linker,
                                                    const float* __restrict__ resL,
                                                    unsigned short* __restrict__ Z,
                                                    unsigned short* __restrict__ TRt,
                                                    unsigned short* __restrict__ W,
                                                    unsigned short* __restrict__ LcatT,
                                                    float* __restrict__ out) {
    __shared__ SMem sm;
    cg::grid_group grid = cg::this_grid();
    int blk = blockIdx.x, t = threadIdx.x;
    int w = t >> 6, l = t & 63;
    int lane15 = l & 15, quad = l >> 4;

    // ================= Phase A =================
    {   // A1: W recurrence — all 512 blocks
        int et = blk & 31, sc = blk >> 5;
        int e0 = et * 512 + t * 2;
        const float* pp = P + (size_t)e0 * 6;
        float4 pa = *(const float4*)(pp);
        float4 pb = *(const float4*)(pp + 4);
        float4 pc = *(const float4*)(pp + 8);
        float pf[12] = { pa.x, pa.y, pa.z, pa.w, pb.x, pb.y, pb.z, pb.w, pc.x, pc.y, pc.z, pc.w };
        const float* qp = periods + (size_t)e0 * 6;
        float4 qa = *(const float4*)(qp);
        float4 qb = *(const float4*)(qp + 4);
        float4 qc = *(const float4*)(qp + 8);
        float iv[12] = { __builtin_amdgcn_rcpf(qa.x), __builtin_amdgcn_rcpf(qa.y),
                         __builtin_amdgcn_rcpf(qa.z), __builtin_amdgcn_rcpf(qa.w),
                         __builtin_amdgcn_rcpf(qb.x), __builtin_amdgcn_rcpf(qb.y),
                         __builtin_amdgcn_rcpf(qb.z), __builtin_amdgcn_rcpf(qb.w),
                         __builtin_amdgcn_rcpf(qc.x), __builtin_amdgcn_rcpf(qc.y),
                         __builtin_amdgcn_rcpf(qc.z), __builtin_amdgcn_rcpf(qc.w) };
        float s0f = (float)(sc * 32);
        float tc[12], cm1[12], cc[12];
        #pragma unroll
        for (int g = 0; g < 12; ++g) {
            tc[g]  = 2.0f * __builtin_amdgcn_cosf(iv[g]);  // 1/p <= 0.5, already in [0,1)
            cm1[g] = __builtin_amdgcn_cosf(__builtin_amdgcn_fractf(s0f * iv[g]));
            cc[g]  = __builtin_amdgcn_cosf(__builtin_amdgcn_fractf((s0f + 1.0f) * iv[g]));
        }
        #pragma unroll 4
        for (int ss = 0; ss < 32; ++ss) {
            float a0 = 0.f, a1 = 0.f;
            #pragma unroll
            for (int g = 0; g < 6; ++g)  a0 += pf[g] * cm1[g];
            #pragma unroll
            for (int g = 6; g < 12; ++g) a1 += pf[g] * cm1[g];
            int s = sc * 32 + ss;
            *(unsigned int*)(W + (size_t)s * 16384 + e0) = pack2(a0, a1);
            #pragma unroll
            for (int g = 0; g < 12; ++g) {
                float cn = fmaf(tc[g], cc[g], -cm1[g]);
                cm1[g] = cc[g]; cc[g] = cn;
            }
        }
    }
    if (blk < 256) {
        // A2: k1 ZR-GEMM + LN (blocks 0..255)
        int r0 = blk * 32;
        const float* wbase = (w < 2) ? M : resW;
        int wco = (w < 2) ? (w * 64) : (w * 64 - 128);
        floatx4 acc[2][4] = {};
        for (int kk = 0; kk < 256; kk += 32) {
            int k0 = kk + quad * 8;
            const float* xr0 = x + (size_t)(r0 + lane15) * 256 + k0;
            const float* xr1 = x + (size_t)(r0 + 16 + lane15) * 256 + k0;
            short8 a0 = pack8(*(const float4*)xr0, *(const float4*)(xr0 + 4));
            short8 a1 = pack8(*(const float4*)xr1, *(const float4*)(xr1 + 4));
            #pragma unroll
            for (int nt = 0; nt < 4; ++nt) {
                const float* br = wbase + (size_t)(wco + nt * 16 + lane15) * 256 + k0;
                short8 b = pack8(*(const float4*)br, *(const float4*)(br + 4));
                acc[0][nt] = __builtin_amdgcn_mfma_f32_16x16x32_bf16(a0, b, acc[0][nt], 0, 0, 0);
                acc[1][nt] = __builtin_amdgcn_mfma_f32_16x16x32_bf16(a1, b, acc[1][nt], 0, 0, 0);
            }
        }
        #pragma unroll
        for (int mt = 0; mt < 2; ++mt)
            #pragma unroll
            for (int nt = 0; nt < 4; ++nt)
                #pragma unroll
                for (int r = 0; r < 4; ++r) {
                    int ro = mt * 16 + quad * 4 + r;
                    int co = w * 64 + nt * 16 + lane15;
                    sm.p1.buf[ro * 258 + co] = acc[mt][nt][r];
                }
        __syncthreads();
        {
            int r = t >> 3, seg = t & 7;
            float s1 = 0.f, s2 = 0.f;
            #pragma unroll
            for (int e = 0; e < 16; ++e) { float v = sm.p1.buf[r * 258 + seg * 16 + e]; s1 += v; s2 += v * v; }
            sm.p1.red1[r * 8 + seg] = s1; sm.p1.red2[r * 8 + seg] = s2;
        }
        __syncthreads();
        if (t < 32) {
            float s1 = 0.f, s2 = 0.f;
            #pragma unroll
            for (int e = 0; e < 8; ++e) { s1 += sm.p1.red1[t * 8 + e]; s2 += sm.p1.red2[t * 8 + e]; }
            float mu = s1 * (1.0f / 128.0f);
            float var = s2 * (1.0f / 128.0f) - mu * mu;
            sm.p1.mus[t] = mu; sm.p1.rsg[t] = rsqrtf(var + LN_EPS);
        }
        __syncthreads();
        int b = r0 >> 9, s0 = r0 & 511;
        {   // Z writeout
            int r = t >> 3, c0 = (t & 7) * 16;
            int grow = r0 + r;
            float mu = sm.p1.mus[r], rs = sm.p1.rsg[r];
            float zv[16];
            #pragma unroll
            for (int e = 0; e < 16; ++e) {
                int j = c0 + e;
                zv[e] = (sm.p1.buf[r * 258 + j] - mu) * rs * gamma[j] + beta[j];
            }
            uint4 oz0, oz1;
            oz0.x = pack2(zv[0], zv[1]);  oz0.y = pack2(zv[2], zv[3]);
            oz0.z = pack2(zv[4], zv[5]);  oz0.w = pack2(zv[6], zv[7]);
            oz1.x = pack2(zv[8], zv[9]);  oz1.y = pack2(zv[10], zv[11]);
            oz1.z = pack2(zv[12], zv[13]); oz1.w = pack2(zv[14], zv[15]);
            *(uint4*)(Z + (size_t)grow * 128 + c0) = oz0;
            *(uint4*)(Z + (size_t)grow * 128 + c0 + 8) = oz1;
        }
        {   // R writeout transposed into TRt[b][j][512+s]
            int j = t >> 1, sh = (t & 1) * 16;
            unsigned int ow[8];
            #pragma unroll
            for (int p = 0; p < 8; ++p) {
                float v0 = sm.p1.buf[(sh + 2 * p) * 258 + 128 + j];
                float v1 = sm.p1.buf[(sh + 2 * p + 1) * 258 + 128 + j];
                ow[p] = pack2(v0, v1);
            }
            unsigned short* dst = TRt + ((size_t)b * 128 + j) * 1024 + 512 + s0 + sh;
            uint4 u0; u0.x = ow[0]; u0.y = ow[1]; u0.z = ow[2]; u0.w = ow[3];
            uint4 u1; u1.x = ow[4]; u1.y = ow[5]; u1.z = ow[6]; u1.w = ow[7];
            *(uint4*)(dst) = u0;
            *(uint4*)(dst + 8) = u1;
        }
    } else if (blk < 288) {
        // A3: LcatT transpose (blocks 256..287)
        int kb = blk - 256;                 // 0..31
        int k0 = kb * 32;
        const float* src = (kb < 16) ? (Linker + (size_t)k0 * 256)
                                     : (resL + (size_t)(k0 - 512) * 256);
        #pragma unroll
        for (int q = 0; q < 8; ++q) {
            int lin = t + 256 * q;
            int row = lin >> 6, col4 = (lin & 63) * 4;
            float4 v = *(const float4*)(src + row * 256 + col4);
            *(unsigned int*)(sm.lcat + row * 260 + col4)     = pack2(v.x, v.y);
            *(unsigned int*)(sm.lcat + row * 260 + col4 + 2) = pack2(v.z, v.w);
        }
        __syncthreads();
        int o = t;
        unsigned int outw[16];
        #pragma unroll
        for (int kp = 0; kp < 16; ++kp) {
            unsigned int lo = sm.lcat[(2 * kp) * 260 + o];
            unsigned int hi = sm.lcat[(2 * kp + 1) * 260 + o];
            outw[kp] = lo | (hi << 16);
        }
        unsigned short* dst = LcatT + (size_t)o * 1024 + k0;
        #pragma unroll
        for (int qq = 0; qq < 4; ++qq) {
            uint4 u; u.x = outw[qq*4]; u.y = outw[qq*4+1]; u.z = outw[qq*4+2]; u.w = outw[qq*4+3];
            *(uint4*)(dst + qq * 8) = u;
        }
    }

    grid.sync();

    // ================= Phase B: k2b — T[b,s,i] -> TRt[b][i][s]; block = one s =================
    {
        int s = blk;
        int i0w = w * 32;
        floatx4 acc[2] = {};
        #pragma unroll
        for (int kk = 0; kk < 4; ++kk) {
            int k0 = kk * 32 + quad * 8;
            short8 a = *(const short8*)(Z + ((size_t)lane15 * 512 + s) * 128 + k0);
            #pragma unroll
            for (int nt = 0; nt < 2; ++nt) {
                short8 bf = *(const short8*)(W + (size_t)s * 16384 + (i0w + nt * 16 + lane15) * 128 + k0);
                acc[nt] = __builtin_amdgcn_mfma_f32_16x16x32_bf16(a, bf, acc[nt], 0, 0, 0);
            }
        }
        #pragma unroll
        for (int nt = 0; nt < 2; ++nt) {
            int i = i0w + nt * 16 + lane15;
            #pragma unroll
            for (int r = 0; r < 4; ++r) {
                int brow = quad * 4 + r;
                TRt[((size_t)brow * 128 + i) * 1024 + s] = f2bf(acc[nt][r]);
            }
        }
    }

    grid.sync();

    // ================= Phase C: k3 — out[b][o][i]; blocks 0..255 =================
    if (blk < 256) {
        int b = blk & 15, ot = (blk >> 4) & 7, it = blk >> 7;
        int o0 = ot * 32, i0 = it * 64;
        const unsigned short* trb = TRt + (size_t)b * 128 * 1024;
        floatx4 acc[2][4] = {};
        #pragma unroll 2
        for (int kk = 0; kk < 8; ++kk) {
            int k0 = w * 256 + kk * 32 + quad * 8;
            short8 afr0 = *(const short8*)(LcatT + (size_t)(o0 + lane15) * 1024 + k0);
            short8 afr1 = *(const short8*)(LcatT + (size_t)(o0 + 16 + lane15) * 1024 + k0);
            #pragma unroll
            for (int nt = 0; nt < 4; ++nt) {
                short8 bfr = *(const short8*)(trb + (size_t)(i0 + nt * 16 + lane15) * 1024 + k0);
                acc[0][nt] = __builtin_amdgcn_mfma_f32_16x16x32_bf16(afr0, bfr, acc[0][nt], 0, 0, 0);
                acc[1][nt] = __builtin_amdgcn_mfma_f32_16x16x32_bf16(afr1, bfr, acc[1][nt], 0, 0, 0);
            }
        }
        __syncthreads();   // sm.red reuse: ensure phase-B has no pending LDS users (none) — and all waves ready
        #pragma unroll
        for (int mt = 0; mt < 2; ++mt)
            #pragma unroll
            for (int nt = 0; nt < 4; ++nt)
                #pragma unroll
                for (int r = 0; r < 4; ++r) {
                    int ro = mt * 16 + quad * 4 + r;
                    int co = nt * 16 + lane15;
                    sm.red[(w * 32 + ro) * 64 + co] = acc[mt][nt][r];
                }
        __syncthreads();
        {
            int ro = t >> 3, c0 = (t & 7) * 8;
            float vs[8];
            #pragma unroll
            for (int e = 0; e < 8; ++e) {
                float sum = 0.f;
                #pragma unroll
                for (int ww = 0; ww < 4; ++ww) sum += sm.red[(ww * 32 + ro) * 64 + c0 + e];
                vs[e] = sum;
            }
            float4 o1 = { vs[0], vs[1], vs[2], vs[3] };
            float4 o2 = { vs[4], vs[5], vs[6], vs[7] };
            size_t ob = ((size_t)b * 256 + o0 + ro) * 128 + i0 + c0;
            *(float4*)(out + ob) = o1;
            *(float4*)(out + ob + 4) = o2;
        }
    }
}

extern "C" void kernel_launch(void* const* d_in, const int* in_sizes, int n_in,
                              void* d_out, int out_size, void* d_ws, size_t ws_size,
                              hipStream_t stream) {
    const float* x      = (const float*)d_in[0];
    const float* M      = (const float*)d_in[1];
    const float* P      = (const float*)d_in[2];
    const float* Linker = (const float*)d_in[3];
    const float* gamma  = (const float*)d_in[4];
    const float* beta   = (const float*)d_in[5];
    const float* resW   = (const float*)d_in[6];
    const float* resL   = (const float*)d_in[7];
    const float* periods= (const float*)d_in[8];
    (void)in_sizes; (void)n_in; (void)out_size; (void)ws_size;

    float* ws = (float*)d_ws;
    // ws layout (float offsets):
    //   LcatT [0,       131072)    256x1024 bf16   [o][k]
    //   Z     [131072,  655360)    8192x128 bf16   [b*512+s][j]
    //   TRt   [655360,  1703936)   16x128x1024 bf16 [b][i][k] (k<512: T(s), k>=512: R(s))
    //   W     [1703936, 5898240)   512x128x128 bf16
    unsigned short* LcatT = (unsigned short*)(ws);
    unsigned short* Z     = (unsigned short*)(ws + 131072);
    unsigned short* TRt   = (unsigned short*)(ws + 655360);
    unsigned short* W     = (unsigned short*)(ws + 1703936);
    float* outp = (float*)d_out;

    void* args[] = { (void*)&x, (void*)&M, (void*)&resW, (void*)&gamma, (void*)&beta,
                     (void*)&P, (void*)&periods, (void*)&Linker, (void*)&resL,
                     (void*)&Z, (void*)&TRt, (void*)&W, (void*)&LcatT, (void*)&outp };
    hipLaunchCooperativeKernel((void*)fused_all, dim3(512), dim3(256), args, 0, stream);
}

// Round 7
// 116.652 us; speedup vs baseline: 2.3256x; 2.3256x over previous
//
#include <hip/hip_runtime.h>
#include <hip/hip_bf16.h>

// Shapes hardcoded: b=16, S=512, IN=256, OUT=128, NB=6, Lo=256, actual_seq_len=512
#define LN_EPS 1e-5f

typedef __attribute__((ext_vector_type(8))) short short8;   // 8 bf16 = 4 VGPR (MFMA A/B frag)
typedef __attribute__((ext_vector_type(4))) float floatx4;  // MFMA C/D frag

__device__ __forceinline__ float bf2f(unsigned int u16) {
    union { unsigned int i; float f; } v; v.i = (u16 & 0xffffu) << 16; return v.f;
}
__device__ __forceinline__ unsigned short f2bf(float f) {
    __hip_bfloat16 h = __float2bfloat16(f);
    union { __hip_bfloat16 h; unsigned short u; } v; v.h = h; return v.u;
}
__device__ __forceinline__ unsigned int pack2(float a, float b) {
    return (unsigned int)f2bf(a) | ((unsigned int)f2bf(b) << 16);
}
__device__ __forceinline__ short8 pack8(float4 a, float4 b) {
    union { short8 s; uint4 u; } v;
    v.u.x = pack2(a.x, a.y); v.u.y = pack2(a.z, a.w);
    v.u.z = pack2(b.x, b.y); v.u.w = pack2(b.z, b.w);
    return v.s;
}

union SMem {
    struct { float buf[32 * 258]; float red1[256]; float red2[256]; float mus[32]; float rsg[32]; } p1;
    unsigned short lcat[32 * 260];
};

// ---------------- s1: all independent producers in one launch (NO grid sync) ----------------
// blk 0..511: W[s][e] via cos recurrence; blk 512..767: k1 ZR-GEMM+LN; blk 768..799: LcatT transpose
__global__ __launch_bounds__(256) void s1_produce(const float* __restrict__ x,
                                                  const float* __restrict__ M,
                                                  const float* __restrict__ resW,
                                                  const float* __restrict__ gamma,
                                                  const float* __restrict__ beta,
                                                  const float* __restrict__ P,
                                                  const float* __restrict__ periods,
                                                  const float* __restrict__ Linker,
                                                  const float* __restrict__ resL,
                                                  unsigned short* __restrict__ Z,
                                                  unsigned short* __restrict__ TRt,
                                                  unsigned short* __restrict__ W,
                                                  unsigned short* __restrict__ LcatT) {
    __shared__ SMem sm;
    int blk = blockIdx.x, t = threadIdx.x;
    int w = t >> 6, l = t & 63;
    int lane15 = l & 15, quad = l >> 4;

    if (blk < 512) {
        // ---- W recurrence ----
        int et = blk & 31, sc = blk >> 5;
        int e0 = et * 512 + t * 2;
        const float* pp = P + (size_t)e0 * 6;
        float4 pa = *(const float4*)(pp);
        float4 pb = *(const float4*)(pp + 4);
        float4 pc = *(const float4*)(pp + 8);
        float pf[12] = { pa.x, pa.y, pa.z, pa.w, pb.x, pb.y, pb.z, pb.w, pc.x, pc.y, pc.z, pc.w };
        const float* qp = periods + (size_t)e0 * 6;
        float4 qa = *(const float4*)(qp);
        float4 qb = *(const float4*)(qp + 4);
        float4 qc = *(const float4*)(qp + 8);
        float iv[12] = { __builtin_amdgcn_rcpf(qa.x), __builtin_amdgcn_rcpf(qa.y),
                         __builtin_amdgcn_rcpf(qa.z), __builtin_amdgcn_rcpf(qa.w),
                         __builtin_amdgcn_rcpf(qb.x), __builtin_amdgcn_rcpf(qb.y),
                         __builtin_amdgcn_rcpf(qb.z), __builtin_amdgcn_rcpf(qb.w),
                         __builtin_amdgcn_rcpf(qc.x), __builtin_amdgcn_rcpf(qc.y),
                         __builtin_amdgcn_rcpf(qc.z), __builtin_amdgcn_rcpf(qc.w) };
        float s0f = (float)(sc * 32);
        float tc[12], cm1[12], cc[12];
        #pragma unroll
        for (int g = 0; g < 12; ++g) {
            tc[g]  = 2.0f * __builtin_amdgcn_cosf(iv[g]);  // 1/p <= 0.5, already in [0,1)
            cm1[g] = __builtin_amdgcn_cosf(__builtin_amdgcn_fractf(s0f * iv[g]));
            cc[g]  = __builtin_amdgcn_cosf(__builtin_amdgcn_fractf((s0f + 1.0f) * iv[g]));
        }
        #pragma unroll 4
        for (int ss = 0; ss < 32; ++ss) {
            float a0 = 0.f, a1 = 0.f;
            #pragma unroll
            for (int g = 0; g < 6; ++g)  a0 += pf[g] * cm1[g];
            #pragma unroll
            for (int g = 6; g < 12; ++g) a1 += pf[g] * cm1[g];
            int s = sc * 32 + ss;
            *(unsigned int*)(W + (size_t)s * 16384 + e0) = pack2(a0, a1);
            #pragma unroll
            for (int g = 0; g < 12; ++g) {
                float cn = fmaf(tc[g], cc[g], -cm1[g]);
                cm1[g] = cc[g]; cc[g] = cn;
            }
        }
    } else if (blk < 768) {
        // ---- k1: ZR = x @ [M;resW]^T, LN on Z half ----
        int r0 = (blk - 512) * 32;
        const float* wbase = (w < 2) ? M : resW;
        int wco = (w < 2) ? (w * 64) : (w * 64 - 128);
        floatx4 acc[2][4] = {};
        for (int kk = 0; kk < 256; kk += 32) {
            int k0 = kk + quad * 8;
            const float* xr0 = x + (size_t)(r0 + lane15) * 256 + k0;
            const float* xr1 = x + (size_t)(r0 + 16 + lane15) * 256 + k0;
            short8 a0 = pack8(*(const float4*)xr0, *(const float4*)(xr0 + 4));
            short8 a1 = pack8(*(const float4*)xr1, *(const float4*)(xr1 + 4));
            #pragma unroll
            for (int nt = 0; nt < 4; ++nt) {
                const float* br = wbase + (size_t)(wco + nt * 16 + lane15) * 256 + k0;
                short8 b = pack8(*(const float4*)br, *(const float4*)(br + 4));
                acc[0][nt] = __builtin_amdgcn_mfma_f32_16x16x32_bf16(a0, b, acc[0][nt], 0, 0, 0);
                acc[1][nt] = __builtin_amdgcn_mfma_f32_16x16x32_bf16(a1, b, acc[1][nt], 0, 0, 0);
            }
        }
        #pragma unroll
        for (int mt = 0; mt < 2; ++mt)
            #pragma unroll
            for (int nt = 0; nt < 4; ++nt)
                #pragma unroll
                for (int r = 0; r < 4; ++r) {
                    int ro = mt * 16 + quad * 4 + r;
                    int co = w * 64 + nt * 16 + lane15;
                    sm.p1.buf[ro * 258 + co] = acc[mt][nt][r];
                }
        __syncthreads();
        {
            int r = t >> 3, seg = t & 7;
            float s1 = 0.f, s2 = 0.f;
            #pragma unroll
            for (int e = 0; e < 16; ++e) { float v = sm.p1.buf[r * 258 + seg * 16 + e]; s1 += v; s2 += v * v; }
            sm.p1.red1[r * 8 + seg] = s1; sm.p1.red2[r * 8 + seg] = s2;
        }
        __syncthreads();
        if (t < 32) {
            float s1 = 0.f, s2 = 0.f;
            #pragma unroll
            for (int e = 0; e < 8; ++e) { s1 += sm.p1.red1[t * 8 + e]; s2 += sm.p1.red2[t * 8 + e]; }
            float mu = s1 * (1.0f / 128.0f);
            float var = s2 * (1.0f / 128.0f) - mu * mu;
            sm.p1.mus[t] = mu; sm.p1.rsg[t] = rsqrtf(var + LN_EPS);
        }
        __syncthreads();
        int b = r0 >> 9, s0 = r0 & 511;
        {   // Z writeout
            int r = t >> 3, c0 = (t & 7) * 16;
            int grow = r0 + r;
            float mu = sm.p1.mus[r], rs = sm.p1.rsg[r];
            float zv[16];
            #pragma unroll
            for (int e = 0; e < 16; ++e) {
                int j = c0 + e;
                zv[e] = (sm.p1.buf[r * 258 + j] - mu) * rs * gamma[j] + beta[j];
            }
            uint4 oz0, oz1;
            oz0.x = pack2(zv[0], zv[1]);  oz0.y = pack2(zv[2], zv[3]);
            oz0.z = pack2(zv[4], zv[5]);  oz0.w = pack2(zv[6], zv[7]);
            oz1.x = pack2(zv[8], zv[9]);  oz1.y = pack2(zv[10], zv[11]);
            oz1.z = pack2(zv[12], zv[13]); oz1.w = pack2(zv[14], zv[15]);
            *(uint4*)(Z + (size_t)grow * 128 + c0) = oz0;
            *(uint4*)(Z + (size_t)grow * 128 + c0 + 8) = oz1;
        }
        {   // R writeout transposed into TRt[b][j][512+s]
            int j = t >> 1, sh = (t & 1) * 16;
            unsigned int ow[8];
            #pragma unroll
            for (int p = 0; p < 8; ++p) {
                float v0 = sm.p1.buf[(sh + 2 * p) * 258 + 128 + j];
                float v1 = sm.p1.buf[(sh + 2 * p + 1) * 258 + 128 + j];
                ow[p] = pack2(v0, v1);
            }
            unsigned short* dst = TRt + ((size_t)b * 128 + j) * 1024 + 512 + s0 + sh;
            uint4 u0; u0.x = ow[0]; u0.y = ow[1]; u0.z = ow[2]; u0.w = ow[3];
            uint4 u1; u1.x = ow[4]; u1.y = ow[5]; u1.z = ow[6]; u1.w = ow[7];
            *(uint4*)(dst) = u0;
            *(uint4*)(dst + 8) = u1;
        }
    } else {
        // ---- LcatT transpose ----
        int kb = blk - 768;                 // 0..31
        int k0 = kb * 32;
        const float* src = (kb < 16) ? (Linker + (size_t)k0 * 256)
                                     : (resL + (size_t)(k0 - 512) * 256);
        #pragma unroll
        for (int q = 0; q < 8; ++q) {
            int lin = t + 256 * q;
            int row = lin >> 6, col4 = (lin & 63) * 4;
            float4 v = *(const float4*)(src + row * 256 + col4);
            *(unsigned int*)(sm.lcat + row * 260 + col4)     = pack2(v.x, v.y);
            *(unsigned int*)(sm.lcat + row * 260 + col4 + 2) = pack2(v.z, v.w);
        }
        __syncthreads();
        int o = t;
        unsigned int outw[16];
        #pragma unroll
        for (int kp = 0; kp < 16; ++kp) {
            unsigned int lo = sm.lcat[(2 * kp) * 260 + o];
            unsigned int hi = sm.lcat[(2 * kp + 1) * 260 + o];
            outw[kp] = lo | (hi << 16);
        }
        unsigned short* dst = LcatT + (size_t)o * 1024 + k0;
        #pragma unroll
        for (int qq = 0; qq < 4; ++qq) {
            uint4 u; u.x = outw[qq*4]; u.y = outw[qq*4+1]; u.z = outw[qq*4+2]; u.w = outw[qq*4+3];
            *(uint4*)(dst + qq * 8) = u;
        }
    }
}

// ---------------- k2b: T[b,s,i] via MFMA -> TRt[b][i][s]; block = 4 waves, one s ----------------
__global__ __launch_bounds__(256) void k2b_t(const unsigned short* __restrict__ W,
                                             const unsigned short* __restrict__ Z,
                                             unsigned short* __restrict__ TRt) {
    int t = threadIdx.x, w = t >> 6, l = t & 63;
    int lane15 = l & 15, quad = l >> 4;
    int s = blockIdx.x;
    int i0w = w * 32;
    floatx4 acc[2] = {};
    #pragma unroll
    for (int kk = 0; kk < 4; ++kk) {
        int k0 = kk * 32 + quad * 8;
        short8 a = *(const short8*)(Z + ((size_t)lane15 * 512 + s) * 128 + k0);
        #pragma unroll
        for (int nt = 0; nt < 2; ++nt) {
            short8 bf = *(const short8*)(W + (size_t)s * 16384 + (i0w + nt * 16 + lane15) * 128 + k0);
            acc[nt] = __builtin_amdgcn_mfma_f32_16x16x32_bf16(a, bf, acc[nt], 0, 0, 0);
        }
    }
    #pragma unroll
    for (int nt = 0; nt < 2; ++nt) {
        int i = i0w + nt * 16 + lane15;
        #pragma unroll
        for (int r = 0; r < 4; ++r) {
            int brow = quad * 4 + r;
            TRt[((size_t)brow * 128 + i) * 1024 + s] = f2bf(acc[nt][r]);
        }
    }
}

// ---------------- k3: out[b][o][i], split-K over 4 waves; B-frags direct from TRt ----------------
__global__ __launch_bounds__(256) void k3_out(const unsigned short* __restrict__ LcatT,
                                              const unsigned short* __restrict__ TRt,
                                              float* __restrict__ out) {
    __shared__ float red[4 * 32 * 64];
    int t = threadIdx.x, w = t >> 6, l = t & 63;
    int lane15 = l & 15, quad = l >> 4;
    int b = blockIdx.x, o0 = blockIdx.y * 32, i0 = blockIdx.z * 64;
    const unsigned short* trb = TRt + (size_t)b * 128 * 1024;
    floatx4 acc[2][4] = {};
    #pragma unroll 2
    for (int kk = 0; kk < 8; ++kk) {
        int k0 = w * 256 + kk * 32 + quad * 8;
        short8 afr0 = *(const short8*)(LcatT + (size_t)(o0 + lane15) * 1024 + k0);
        short8 afr1 = *(const short8*)(LcatT + (size_t)(o0 + 16 + lane15) * 1024 + k0);
        #pragma unroll
        for (int nt = 0; nt < 4; ++nt) {
            short8 bfr = *(const short8*)(trb + (size_t)(i0 + nt * 16 + lane15) * 1024 + k0);
            acc[0][nt] = __builtin_amdgcn_mfma_f32_16x16x32_bf16(afr0, bfr, acc[0][nt], 0, 0, 0);
            acc[1][nt] = __builtin_amdgcn_mfma_f32_16x16x32_bf16(afr1, bfr, acc[1][nt], 0, 0, 0);
        }
    }
    #pragma unroll
    for (int mt = 0; mt < 2; ++mt)
        #pragma unroll
        for (int nt = 0; nt < 4; ++nt)
            #pragma unroll
            for (int r = 0; r < 4; ++r) {
                int ro = mt * 16 + quad * 4 + r;
                int co = nt * 16 + lane15;
                red[(w * 32 + ro) * 64 + co] = acc[mt][nt][r];
            }
    __syncthreads();
    {
        int ro = t >> 3, c0 = (t & 7) * 8;
        float vs[8];
        #pragma unroll
        for (int e = 0; e < 8; ++e) {
            float sum = 0.f;
            #pragma unroll
            for (int ww = 0; ww < 4; ++ww) sum += red[(ww * 32 + ro) * 64 + c0 + e];
            vs[e] = sum;
        }
        float4 o1 = { vs[0], vs[1], vs[2], vs[3] };
        float4 o2 = { vs[4], vs[5], vs[6], vs[7] };
        size_t ob = ((size_t)b * 256 + o0 + ro) * 128 + i0 + c0;
        *(float4*)(out + ob) = o1;
        *(float4*)(out + ob + 4) = o2;
    }
}

extern "C" void kernel_launch(void* const* d_in, const int* in_sizes, int n_in,
                              void* d_out, int out_size, void* d_ws, size_t ws_size,
                              hipStream_t stream) {
    const float* x      = (const float*)d_in[0];
    const float* M      = (const float*)d_in[1];
    const float* P      = (const float*)d_in[2];
    const float* Linker = (const float*)d_in[3];
    const float* gamma  = (const float*)d_in[4];
    const float* beta   = (const float*)d_in[5];
    const float* resW   = (const float*)d_in[6];
    const float* resL   = (const float*)d_in[7];
    const float* periods= (const float*)d_in[8];
    (void)in_sizes; (void)n_in; (void)out_size; (void)ws_size;

    float* ws = (float*)d_ws;
    // ws layout (float offsets):
    //   LcatT [0,       131072)    256x1024 bf16   [o][k]
    //   Z     [131072,  655360)    8192x128 bf16   [b*512+s][j]
    //   TRt   [655360,  1703936)   16x128x1024 bf16 [b][i][k] (k<512: T(s), k>=512: R(s))
    //   W     [1703936, 5898240)   512x128x128 bf16
    unsigned short* LcatT = (unsigned short*)(ws);
    unsigned short* Z     = (unsigned short*)(ws + 131072);
    unsigned short* TRt   = (unsigned short*)(ws + 655360);
    unsigned short* W     = (unsigned short*)(ws + 1703936);

    s1_produce<<<800, 256, 0, stream>>>(x, M, resW, gamma, beta, P, periods,
                                        Linker, resL, Z, TRt, W, LcatT);
    k2b_t<<<512, 256, 0, stream>>>(W, Z, TRt);
    k3_out<<<dim3(16, 8, 2), 256, 0, stream>>>(LcatT, TRt, (float*)d_out);
}